// Round 5
// baseline (442.678 us; speedup 1.0000x reference)
//
#include <hip/hip_runtime.h>

#define B_ 2
#define C_ 256
#define N_ 8192
#define NG_ 32

typedef unsigned int u32;
using f32x4 = __attribute__((ext_vector_type(4))) float;
using s8v   = __attribute__((ext_vector_type(8))) short;   // 8 x bf16 (4 VGPR)

__device__ __forceinline__ unsigned short f2bf(float f) {
  unsigned u = __builtin_bit_cast(unsigned, f);
  return (unsigned short)((u + 0x7fffu + ((u >> 16) & 1u)) >> 16);
}
__device__ __forceinline__ float bf2f(unsigned short h) {
  return __builtin_bit_cast(float, (u32)h << 16);
}

// ---------------- weight fp32 -> bf16 (4 x 256x256, contiguous out) ---------
__global__ void cvt_w_kernel(const float* __restrict__ wq, const float* __restrict__ wk,
                             const float* __restrict__ wv, const float* __restrict__ wp,
                             unsigned short* __restrict__ out) {
  int i = blockIdx.x * 256 + threadIdx.x;        // 262144 total
  int m = i >> 16;
  const float* src = m == 0 ? wq : m == 1 ? wk : m == 2 ? wv : wp;
  out[i] = f2bf(src[i & 65535]);
}

// ---------------- groupnorm pass 1: mean/rstd per (b, group) ----------------
__global__ void gn_stats_kernel(const float* __restrict__ x,
                                float* __restrict__ mean, float* __restrict__ rstd) {
  int bg = blockIdx.x;                                  // 64 groups total
  const f32x4* p = (const f32x4*)(x + (size_t)bg * (8 * N_));
  float s = 0.f, sq = 0.f;
  for (int i = threadIdx.x; i < 8 * N_ / 4; i += 256) {
    f32x4 v = p[i];
    s  += v.x + v.y + v.z + v.w;
    sq += v.x * v.x + v.y * v.y + v.z * v.z + v.w * v.w;
  }
  #pragma unroll
  for (int o = 32; o; o >>= 1) { s += __shfl_down(s, o); sq += __shfl_down(sq, o); }
  __shared__ float ls[4], lq[4];
  int w = threadIdx.x >> 6;
  if ((threadIdx.x & 63) == 0) { ls[w] = s; lq[w] = sq; }
  __syncthreads();
  if (threadIdx.x == 0) {
    s = ls[0] + ls[1] + ls[2] + ls[3];
    sq = lq[0] + lq[1] + lq[2] + lq[3];
    float m = s / (8.f * N_);
    float var = sq / (8.f * N_) - m * m;
    mean[bg] = m;
    rstd[bg] = rsqrtf(var + 1e-5f);
  }
}

// -------- groupnorm pass 2: normalize + transpose -> h[N][C] bf16 -----------
__global__ __launch_bounds__(256) void gn_apply_kernel(
    const float* __restrict__ x, const float* __restrict__ gw, const float* __restrict__ gb,
    const float* __restrict__ mean, const float* __restrict__ rstd,
    unsigned short* __restrict__ h) {
  __shared__ unsigned short lds[256][72];
  int b = blockIdx.y, n0 = blockIdx.x * 64;
  const float* xb = x + (size_t)b * C_ * N_;
  int col = threadIdx.x & 63;
  int c0  = threadIdx.x >> 6;
  for (int r = 0; r < 64; ++r) {
    int c = r * 4 + c0;
    float v = xb[(size_t)c * N_ + n0 + col];
    int g = b * NG_ + (c >> 3);
    lds[c][col] = f2bf((v - mean[g]) * rstd[g] * gw[c] + gb[c]);
  }
  __syncthreads();
  int nl = threadIdx.x >> 2;                      // 0..63
  int cb = threadIdx.x & 3;                       // 0..3 (64-channel chunk)
  unsigned short* dst = h + ((size_t)b * N_ + n0 + nl) * C_ + cb * 64;
  #pragma unroll
  for (int g2 = 0; g2 < 8; ++g2) {
    s8v v;
    #pragma unroll
    for (int e = 0; e < 8; ++e) v[e] = (short)lds[cb * 64 + g2 * 8 + e][nl];
    *(s8v*)(dst + g2 * 8) = v;
  }
}

// -------- generic C[i][j] = sum_k A[i][k]*B[j][k] (bf16 in, K=256) ----------
template <int MODE>
__global__ __launch_bounds__(256) void gemm_nt_kernel(
    const unsigned short* __restrict__ A, long sA,
    const unsigned short* __restrict__ Bm, long sB,
    const float* __restrict__ bias,
    const float* __restrict__ resid, long sR,
    void* __restrict__ outv, long sO, int ldo) {
  int b = blockIdx.z;
  const unsigned short* Ab = A + (size_t)b * sA;
  const unsigned short* Bb = Bm + (size_t)b * sB;
  int i0 = blockIdx.x * 64, j0 = blockIdx.y * 64;
  int lane = threadIdx.x & 63, w = threadIdx.x >> 6;
  int l15 = lane & 15, lg = lane >> 4;
  const unsigned short* Ap = Ab + (size_t)(i0 + w * 16 + l15) * 256 + lg * 8;
  const unsigned short* Bp = Bb + (size_t)(j0 + l15) * 256 + lg * 8;
  f32x4 acc[4];
  #pragma unroll
  for (int jt = 0; jt < 4; ++jt) acc[jt] = f32x4{0.f, 0.f, 0.f, 0.f};
  #pragma unroll
  for (int kt = 0; kt < 8; ++kt) {
    s8v a = *(const s8v*)(Ap + kt * 32);
    #pragma unroll
    for (int jt = 0; jt < 4; ++jt) {
      s8v bb = *(const s8v*)(Bp + (size_t)jt * 16 * 256 + kt * 32);
      acc[jt] = __builtin_amdgcn_mfma_f32_16x16x32_bf16(a, bb, acc[jt], 0, 0, 0);
    }
  }
  int rowb = i0 + w * 16 + lg * 4;
  if (MODE == 0) {
    unsigned short* o = (unsigned short*)outv + (size_t)b * sO;
    #pragma unroll
    for (int jt = 0; jt < 4; ++jt) {
      int j = j0 + jt * 16 + l15;
      float bj = bias[j];
      #pragma unroll
      for (int r = 0; r < 4; ++r)
        o[(size_t)(rowb + r) * ldo + j] = f2bf(acc[jt][r] + bj);
    }
  } else if (MODE == 1) {
    unsigned short* o = (unsigned short*)outv + (size_t)b * sO;
    #pragma unroll
    for (int jt = 0; jt < 4; ++jt) {
      int j = j0 + jt * 16 + l15;
      #pragma unroll
      for (int r = 0; r < 4; ++r)
        o[(size_t)(rowb + r) * ldo + j] = f2bf(acc[jt][r] + bias[rowb + r]);
    }
  } else {
    float* o = (float*)outv + (size_t)b * sO;
    const float* xr = resid + (size_t)b * sR;
    #pragma unroll
    for (int jt = 0; jt < 4; ++jt) {
      int j = j0 + jt * 16 + l15;
      #pragma unroll
      for (int r = 0; r < 4; ++r) {
        size_t idx = (size_t)(rowb + r) * ldo + j;
        o[idx] = acc[jt][r] + bias[rowb + r] + xr[idx];
      }
    }
  }
}

// ---------------- flash attention pass 1 ------------------------------------
// grid (64 qblk, 4 kv-slice, 2 batch), 256 thr = 4 waves, 32 q-rows/wave.
// KVBLK=32, double-buffered K/V staged via global_load_lds (K pre-swizzled at
// the global source so LDS dest stays linear). Writes normalized bf16 partial
// O + LSE per (slice,row); merge kernel combines the 4 slices.
// LDS shorts: K 2x[32][256]=16384 | V 2x[256][32]=16384 | P 4x[32][40]=5120
//   -> 75776 B. 2 blocks/CU (151552 <= 163840), 2 waves/SIMD.
__global__ __launch_bounds__(256, 2) void attn_kernel(
    const unsigned short* __restrict__ Q, const unsigned short* __restrict__ K,
    const unsigned short* __restrict__ V, unsigned short* __restrict__ Op,
    float* __restrict__ lse) {
  extern __shared__ unsigned short smem[];
  int qb = blockIdx.x, sl = blockIdx.y, b = blockIdx.z;
  int q0 = qb * 128;
  int kvbase = sl * 2048;
  int t = threadIdx.x, lane = t & 63, w = t >> 6;
  int l15 = lane & 15, lg = lane >> 4;
  unsigned short* Pw = smem + 32768 + w * 1280;          // [32][40] shorts

  const unsigned short* Qg = Q + ((size_t)b * N_ + q0 + w * 32) * 256;
  const unsigned short* Kg = K + ((size_t)b * N_ + kvbase) * 256;
  const unsigned short* Vg = V + (size_t)b * 256 * N_ + kvbase;
  const float sc = 0.0625f * 1.44269504088896f;          // C^-0.5 * log2(e)

  // hoist Q fragments: 2 row-blocks x 8 k-steps
  s8v qf[2][8];
  #pragma unroll
  for (int rb = 0; rb < 2; ++rb)
    #pragma unroll
    for (int kt = 0; kt < 8; ++kt)
      qf[rb][kt] = *(const s8v*)(Qg + (size_t)(rb * 16 + l15) * 256 + kt * 32 + lg * 8);

  f32x4 o_acc[2][16];
  #pragma unroll
  for (int rb = 0; rb < 2; ++rb)
    #pragma unroll
    for (int ct = 0; ct < 16; ++ct) o_acc[rb][ct] = f32x4{0.f, 0.f, 0.f, 0.f};
  float m_r[2][4], l_r[2][4];
  #pragma unroll
  for (int rb = 0; rb < 2; ++rb)
    #pragma unroll
    for (int r = 0; r < 4; ++r) { m_r[rb][r] = -1e30f; l_r[rb][r] = 0.f; }

  // async stage: K tile [32][256] (source pre-swizzled), V tile [256][32]
  auto stage = [&](int it, int bufsel) {
    unsigned short* Kd = smem + bufsel * 8192;
    unsigned short* Vd = smem + 16384 + bufsel * 8192;
    const unsigned short* Ks = Kg + (size_t)it * 32 * 256;
    const unsigned short* Vs = Vg + it * 32;
    #pragma unroll
    for (int i = 0; i < 4; ++i) {
      int slot = i * 256 + t;
      int mm = slot >> 5, c = slot & 31;
      const unsigned short* src = Ks + (size_t)mm * 256 + ((c ^ (mm & 7)) << 3);
      unsigned short* dst = Kd + (i * 256 + w * 64) * 8;
      __builtin_amdgcn_global_load_lds(
          (const __attribute__((address_space(1))) u32*)src,
          (__attribute__((address_space(3))) u32*)dst, 16, 0, 0);
    }
    #pragma unroll
    for (int i = 0; i < 4; ++i) {
      int slot = i * 256 + t;
      int cc = slot >> 2, c = slot & 3;
      const unsigned short* src = Vs + (size_t)cc * N_ + c * 8;
      unsigned short* dst = Vd + (i * 256 + w * 64) * 8;
      __builtin_amdgcn_global_load_lds(
          (const __attribute__((address_space(1))) u32*)src,
          (__attribute__((address_space(3))) u32*)dst, 16, 0, 0);
    }
  };

  stage(0, 0);
  __syncthreads();

  for (int it = 0; it < 64; ++it) {
    int cur = it & 1;
    if (it + 1 < 64) stage(it + 1, cur ^ 1);   // prefetch into other buffer
    const unsigned short* Kd = smem + cur * 8192;
    const unsigned short* Vd = smem + 16384 + cur * 8192;

    // S = Q K^T : 2 row-blocks x 2 col-tiles, K-frags shared across row-blocks
    f32x4 sv[2][2];
    #pragma unroll
    for (int rb = 0; rb < 2; ++rb)
      #pragma unroll
      for (int jt = 0; jt < 2; ++jt) sv[rb][jt] = f32x4{0.f, 0.f, 0.f, 0.f};
    #pragma unroll
    for (int kt = 0; kt < 8; ++kt) {
      #pragma unroll
      for (int jt = 0; jt < 2; ++jt) {
        int row = jt * 16 + l15;
        s8v kb = *(const s8v*)((const char*)Kd + row * 512 +
                               ((kt * 64 + lg * 16) ^ ((row & 7) << 4)));
        sv[0][jt] = __builtin_amdgcn_mfma_f32_16x16x32_bf16(qf[0][kt], kb, sv[0][jt], 0, 0, 0);
        sv[1][jt] = __builtin_amdgcn_mfma_f32_16x16x32_bf16(qf[1][kt], kb, sv[1][jt], 0, 0, 0);
      }
    }

    // online softmax (log2 domain), defer-max rescale (T13, THR=8)
    float rm[2][4];
    #pragma unroll
    for (int rb = 0; rb < 2; ++rb)
      #pragma unroll
      for (int r = 0; r < 4; ++r) rm[rb][r] = fmaxf(sv[rb][0][r], sv[rb][1][r]);
    #pragma unroll
    for (int o = 1; o < 16; o <<= 1)
      #pragma unroll
      for (int rb = 0; rb < 2; ++rb)
        #pragma unroll
        for (int r = 0; r < 4; ++r) rm[rb][r] = fmaxf(rm[rb][r], __shfl_xor(rm[rb][r], o));
    bool ok = true;
    #pragma unroll
    for (int rb = 0; rb < 2; ++rb)
      #pragma unroll
      for (int r = 0; r < 4; ++r) {
        rm[rb][r] *= sc;
        ok = ok && (rm[rb][r] <= m_r[rb][r] + 8.f);
      }
    if (!__all(ok)) {
      float cr[2][4];
      #pragma unroll
      for (int rb = 0; rb < 2; ++rb)
        #pragma unroll
        for (int r = 0; r < 4; ++r) {
          float mn = fmaxf(m_r[rb][r], rm[rb][r]);
          cr[rb][r] = exp2f(m_r[rb][r] - mn);
          m_r[rb][r] = mn;
          l_r[rb][r] *= cr[rb][r];
        }
      #pragma unroll
      for (int rb = 0; rb < 2; ++rb)
        #pragma unroll
        for (int ct = 0; ct < 16; ++ct)
          #pragma unroll
          for (int r = 0; r < 4; ++r) o_acc[rb][ct][r] *= cr[rb][r];
    }
    float rs[2][4];
    #pragma unroll
    for (int rb = 0; rb < 2; ++rb)
      #pragma unroll
      for (int r = 0; r < 4; ++r) rs[rb][r] = 0.f;
    #pragma unroll
    for (int rb = 0; rb < 2; ++rb)
      #pragma unroll
      for (int jt = 0; jt < 2; ++jt)
        #pragma unroll
        for (int r = 0; r < 4; ++r) {
          float p = exp2f(__builtin_fmaf(sv[rb][jt][r], sc, -m_r[rb][r]));
          sv[rb][jt][r] = p;
          rs[rb][r] += p;
        }
    #pragma unroll
    for (int o = 1; o < 16; o <<= 1)
      #pragma unroll
      for (int rb = 0; rb < 2; ++rb)
        #pragma unroll
        for (int r = 0; r < 4; ++r) rs[rb][r] += __shfl_xor(rs[rb][r], o);
    #pragma unroll
    for (int rb = 0; rb < 2; ++rb)
      #pragma unroll
      for (int r = 0; r < 4; ++r) l_r[rb][r] += rs[rb][r];

    // P -> wave-private LDS [32][40] (conflict-free by stride), read back A-frags
    #pragma unroll
    for (int rb = 0; rb < 2; ++rb)
      #pragma unroll
      for (int jt = 0; jt < 2; ++jt)
        #pragma unroll
        for (int r = 0; r < 4; ++r)
          Pw[(rb * 16 + lg * 4 + r) * 40 + jt * 16 + l15] = f2bf(sv[rb][jt][r]);
    s8v pa[2];
    #pragma unroll
    for (int rb = 0; rb < 2; ++rb)
      pa[rb] = *(const s8v*)(Pw + (rb * 16 + l15) * 40 + lg * 8);

    // O += P V : V-frags shared across row-blocks
    #pragma unroll
    for (int ct = 0; ct < 16; ++ct) {
      s8v vb = *(const s8v*)(Vd + (ct * 16 + l15) * 32 + lg * 8);
      o_acc[0][ct] = __builtin_amdgcn_mfma_f32_16x16x32_bf16(pa[0], vb, o_acc[0][ct], 0, 0, 0);
      o_acc[1][ct] = __builtin_amdgcn_mfma_f32_16x16x32_bf16(pa[1], vb, o_acc[1][ct], 0, 0, 0);
    }
    __syncthreads();
  }

  // epilogue: normalized bf16 partial + LSE
  #pragma unroll
  for (int rb = 0; rb < 2; ++rb) {
    float inv[4];
    #pragma unroll
    for (int r = 0; r < 4; ++r) inv[r] = 1.f / l_r[rb][r];
    int rid0 = b * N_ + q0 + w * 32 + rb * 16;
    if (l15 == 0) {
      #pragma unroll
      for (int r = 0; r < 4; ++r)
        lse[sl * (B_ * N_) + rid0 + lg * 4 + r] = m_r[rb][r] + log2f(l_r[rb][r]);
    }
    unsigned short* Od = Op + ((size_t)sl * (B_ * N_) + rid0) * 256;
    #pragma unroll
    for (int ct = 0; ct < 16; ++ct)
      #pragma unroll
      for (int r = 0; r < 4; ++r)
        Od[(size_t)(lg * 4 + r) * 256 + ct * 16 + l15] = f2bf(o_acc[rb][ct][r] * inv[r]);
  }
}

// ---------------- merge the 4 KV-slice partials ------------------------------
__global__ __launch_bounds__(256) void attn_merge_kernel(
    const unsigned short* __restrict__ Op, const float* __restrict__ lse,
    unsigned short* __restrict__ Ob) {
  int gid = blockIdx.x * 256 + threadIdx.x;      // 524288 = 16384 rows x 32 chunks
  int row = gid >> 5;
  int co = (gid & 31) * 8;
  float L[4], lm = -1e30f;
  #pragma unroll
  for (int s = 0; s < 4; ++s) { L[s] = lse[s * (B_ * N_) + row]; lm = fmaxf(lm, L[s]); }
  float acc[8];
  #pragma unroll
  for (int e = 0; e < 8; ++e) acc[e] = 0.f;
  float wsum = 0.f;
  #pragma unroll
  for (int s = 0; s < 4; ++s) {
    float wg = exp2f(L[s] - lm);
    wsum += wg;
    s8v v = *(const s8v*)(Op + ((size_t)s * (B_ * N_) + row) * 256 + co);
    #pragma unroll
    for (int e = 0; e < 8; ++e) acc[e] += wg * bf2f((unsigned short)v[e]);
  }
  float inv = 1.f / wsum;
  s8v o;
  #pragma unroll
  for (int e = 0; e < 8; ++e) o[e] = (short)f2bf(acc[e] * inv);
  *(s8v*)(Ob + (size_t)row * 256 + co) = o;
}

// ---------------------------------------------------------------------------
extern "C" void kernel_launch(void* const* d_in, const int* in_sizes, int n_in,
                              void* d_out, int out_size, void* d_ws, size_t ws_size,
                              hipStream_t stream) {
  (void)in_sizes; (void)n_in; (void)out_size; (void)ws_size;
  const float* x  = (const float*)d_in[0];
  const float* gw = (const float*)d_in[1];
  const float* gb = (const float*)d_in[2];
  const float* wq = (const float*)d_in[3];
  const float* bq = (const float*)d_in[4];
  const float* wk = (const float*)d_in[5];
  const float* bk = (const float*)d_in[6];
  const float* wv = (const float*)d_in[7];
  const float* bv = (const float*)d_in[8];
  const float* wp = (const float*)d_in[9];
  const float* bp = (const float*)d_in[10];

  const size_t HS = (size_t)N_ * C_;              // per-batch elems
  char* ws = (char*)d_ws;
  unsigned short* wqb = (unsigned short*)ws;             // 512 KB
  float* meanp = (float*)(ws + 524288);
  float* rstdp = meanp + 64;
  unsigned short* h    = (unsigned short*)(ws + 525312); // 8 MB  [B][N][C]
  unsigned short* Qb   = h  + B_ * HS;                   // 8 MB  [B][N][C]
  unsigned short* Kb   = Qb + B_ * HS;                   // 8 MB  [B][N][C]
  unsigned short* Vb   = Kb + B_ * HS;                   // 8 MB  [B][C][N]
  unsigned short* Ob   = Vb + B_ * HS;                   // 8 MB  [B][N][C]
  unsigned short* Opart = Ob + B_ * HS;                  // 32 MB [4][B*N][C]
  float* lsep = (float*)(Opart + 4 * B_ * HS);           // 256 KB [4][B*N]
  // total ws use ~72.8 MB

  cvt_w_kernel<<<1024, 256, 0, stream>>>(wq, wk, wv, wp, wqb);
  gn_stats_kernel<<<B_ * NG_, 256, 0, stream>>>(x, meanp, rstdp);
  gn_apply_kernel<<<dim3(N_ / 64, B_), 256, 0, stream>>>(x, gw, gb, meanp, rstdp, h);

  unsigned short* wkb = wqb + 65536;
  unsigned short* wvb = wkb + 65536;
  unsigned short* wpb = wvb + 65536;
  gemm_nt_kernel<0><<<dim3(N_ / 64, C_ / 64, B_), 256, 0, stream>>>(
      h, (long)HS, wqb, 0, bq, nullptr, 0, Qb, (long)HS, C_);
  gemm_nt_kernel<0><<<dim3(N_ / 64, C_ / 64, B_), 256, 0, stream>>>(
      h, (long)HS, wkb, 0, bk, nullptr, 0, Kb, (long)HS, C_);
  gemm_nt_kernel<1><<<dim3(C_ / 64, N_ / 64, B_), 256, 0, stream>>>(
      wvb, 0, h, (long)HS, bv, nullptr, 0, Vb, (long)HS, N_);

  // flash attention pass 1: 4 KV slices, dbuf LDS = 75776 B
  const int attn_lds = 75776;
  hipFuncSetAttribute(reinterpret_cast<const void*>(attn_kernel),
                      hipFuncAttributeMaxDynamicSharedMemorySize, attn_lds);
  attn_kernel<<<dim3(N_ / 128, 4, B_), 256, attn_lds, stream>>>(Qb, Kb, Vb, Opart, lsep);

  // merge 4 slices -> Ob
  attn_merge_kernel<<<(B_ * N_ * 32) / 256, 256, 0, stream>>>(Opart, lsep, Ob);

  // out[o][n] = wp . O[n][:] + bp + x
  gemm_nt_kernel<2><<<dim3(C_ / 64, N_ / 64, B_), 256, 0, stream>>>(
      wpb, 0, Ob, (long)HS, bp, x, (long)HS, d_out, (long)HS, N_);
}

// Round 6
// 441.427 us; speedup vs baseline: 1.0028x; 1.0028x over previous
//
#include <hip/hip_runtime.h>

#define B_ 2
#define C_ 256
#define N_ 8192
#define NG_ 32

typedef unsigned int u32;
using f32x4 = __attribute__((ext_vector_type(4))) float;
using s8v   = __attribute__((ext_vector_type(8))) short;   // 8 x bf16 (4 VGPR)

__device__ __forceinline__ unsigned short f2bf(float f) {
  unsigned u = __builtin_bit_cast(unsigned, f);
  return (unsigned short)((u + 0x7fffu + ((u >> 16) & 1u)) >> 16);
}
__device__ __forceinline__ float bf2f(unsigned short h) {
  return __builtin_bit_cast(float, (u32)h << 16);
}

// ---------------- weight fp32 -> bf16 (4 x 256x256, contiguous out) ---------
__global__ void cvt_w_kernel(const float* __restrict__ wq, const float* __restrict__ wk,
                             const float* __restrict__ wv, const float* __restrict__ wp,
                             unsigned short* __restrict__ out) {
  int i = blockIdx.x * 256 + threadIdx.x;        // 262144 total
  int m = i >> 16;
  const float* src = m == 0 ? wq : m == 1 ? wk : m == 2 ? wv : wp;
  out[i] = f2bf(src[i & 65535]);
}

// ---------------- groupnorm pass 1: mean/rstd per (b, group) ----------------
__global__ void gn_stats_kernel(const float* __restrict__ x,
                                float* __restrict__ mean, float* __restrict__ rstd) {
  int bg = blockIdx.x;                                  // 64 groups total
  const f32x4* p = (const f32x4*)(x + (size_t)bg * (8 * N_));
  float s = 0.f, sq = 0.f;
  for (int i = threadIdx.x; i < 8 * N_ / 4; i += 256) {
    f32x4 v = p[i];
    s  += v.x + v.y + v.z + v.w;
    sq += v.x * v.x + v.y * v.y + v.z * v.z + v.w * v.w;
  }
  #pragma unroll
  for (int o = 32; o; o >>= 1) { s += __shfl_down(s, o); sq += __shfl_down(sq, o); }
  __shared__ float ls[4], lq[4];
  int w = threadIdx.x >> 6;
  if ((threadIdx.x & 63) == 0) { ls[w] = s; lq[w] = sq; }
  __syncthreads();
  if (threadIdx.x == 0) {
    s = ls[0] + ls[1] + ls[2] + ls[3];
    sq = lq[0] + lq[1] + lq[2] + lq[3];
    float m = s / (8.f * N_);
    float var = sq / (8.f * N_) - m * m;
    mean[bg] = m;
    rstd[bg] = rsqrtf(var + 1e-5f);
  }
}

// -------- groupnorm pass 2: normalize + transpose -> h[N][C] bf16 -----------
__global__ __launch_bounds__(256) void gn_apply_kernel(
    const float* __restrict__ x, const float* __restrict__ gw, const float* __restrict__ gb,
    const float* __restrict__ mean, const float* __restrict__ rstd,
    unsigned short* __restrict__ h) {
  __shared__ unsigned short lds[256][72];
  int b = blockIdx.y, n0 = blockIdx.x * 64;
  const float* xb = x + (size_t)b * C_ * N_;
  int col = threadIdx.x & 63;
  int c0  = threadIdx.x >> 6;
  for (int r = 0; r < 64; ++r) {
    int c = r * 4 + c0;
    float v = xb[(size_t)c * N_ + n0 + col];
    int g = b * NG_ + (c >> 3);
    lds[c][col] = f2bf((v - mean[g]) * rstd[g] * gw[c] + gb[c]);
  }
  __syncthreads();
  int nl = threadIdx.x >> 2;                      // 0..63
  int cb = threadIdx.x & 3;                       // 0..3 (64-channel chunk)
  unsigned short* dst = h + ((size_t)b * N_ + n0 + nl) * C_ + cb * 64;
  #pragma unroll
  for (int g2 = 0; g2 < 8; ++g2) {
    s8v v;
    #pragma unroll
    for (int e = 0; e < 8; ++e) v[e] = (short)lds[cb * 64 + g2 * 8 + e][nl];
    *(s8v*)(dst + g2 * 8) = v;
  }
}

// -------- generic C[i][j] = sum_k A[i][k]*B[j][k] (bf16 in, K=256) ----------
template <int MODE>
__global__ __launch_bounds__(256) void gemm_nt_kernel(
    const unsigned short* __restrict__ A, long sA,
    const unsigned short* __restrict__ Bm, long sB,
    const float* __restrict__ bias,
    const float* __restrict__ resid, long sR,
    void* __restrict__ outv, long sO, int ldo) {
  int b = blockIdx.z;
  const unsigned short* Ab = A + (size_t)b * sA;
  const unsigned short* Bb = Bm + (size_t)b * sB;
  int i0 = blockIdx.x * 64, j0 = blockIdx.y * 64;
  int lane = threadIdx.x & 63, w = threadIdx.x >> 6;
  int l15 = lane & 15, lg = lane >> 4;
  const unsigned short* Ap = Ab + (size_t)(i0 + w * 16 + l15) * 256 + lg * 8;
  const unsigned short* Bp = Bb + (size_t)(j0 + l15) * 256 + lg * 8;
  f32x4 acc[4];
  #pragma unroll
  for (int jt = 0; jt < 4; ++jt) acc[jt] = f32x4{0.f, 0.f, 0.f, 0.f};
  #pragma unroll
  for (int kt = 0; kt < 8; ++kt) {
    s8v a = *(const s8v*)(Ap + kt * 32);
    #pragma unroll
    for (int jt = 0; jt < 4; ++jt) {
      s8v bb = *(const s8v*)(Bp + (size_t)jt * 16 * 256 + kt * 32);
      acc[jt] = __builtin_amdgcn_mfma_f32_16x16x32_bf16(a, bb, acc[jt], 0, 0, 0);
    }
  }
  int rowb = i0 + w * 16 + lg * 4;
  if (MODE == 0) {
    unsigned short* o = (unsigned short*)outv + (size_t)b * sO;
    #pragma unroll
    for (int jt = 0; jt < 4; ++jt) {
      int j = j0 + jt * 16 + l15;
      float bj = bias[j];
      #pragma unroll
      for (int r = 0; r < 4; ++r)
        o[(size_t)(rowb + r) * ldo + j] = f2bf(acc[jt][r] + bj);
    }
  } else if (MODE == 1) {
    unsigned short* o = (unsigned short*)outv + (size_t)b * sO;
    #pragma unroll
    for (int jt = 0; jt < 4; ++jt) {
      int j = j0 + jt * 16 + l15;
      #pragma unroll
      for (int r = 0; r < 4; ++r)
        o[(size_t)(rowb + r) * ldo + j] = f2bf(acc[jt][r] + bias[rowb + r]);
    }
  } else {
    float* o = (float*)outv + (size_t)b * sO;
    const float* xr = resid + (size_t)b * sR;
    #pragma unroll
    for (int jt = 0; jt < 4; ++jt) {
      int j = j0 + jt * 16 + l15;
      #pragma unroll
      for (int r = 0; r < 4; ++r) {
        size_t idx = (size_t)(rowb + r) * ldo + j;
        o[idx] = acc[jt][r] + bias[rowb + r] + xr[idx];
      }
    }
  }
}

// ---------------- flash attention pass 1 ------------------------------------
// grid (64 qblk, 4 kv-slice, 2 batch), 256 thr = 4 waves, 32 q-rows/wave.
// KVBLK=32, double-buffered K/V staged via global_load_lds (K pre-swizzled at
// the global source so LDS dest stays linear). Writes normalized bf16 partial
// O + LSE per (slice,row); merge kernel combines the 4 slices.
// LDS shorts: K 2x[32][256]=16384 | V 2x[256][32]=16384 | P 4x[32][40]=5120
//   -> 75776 B. 2 blocks/CU (151552 <= 163840), 2 waves/SIMD.
__global__ __launch_bounds__(256, 2) void attn_kernel(
    const unsigned short* __restrict__ Q, const unsigned short* __restrict__ K,
    const unsigned short* __restrict__ V, unsigned short* __restrict__ Op,
    float* __restrict__ lse) {
  extern __shared__ unsigned short smem[];
  int qb = blockIdx.x, sl = blockIdx.y, b = blockIdx.z;
  int q0 = qb * 128;
  int kvbase = sl * 2048;
  int t = threadIdx.x, lane = t & 63, w = t >> 6;
  int l15 = lane & 15, lg = lane >> 4;
  unsigned short* Pw = smem + 32768 + w * 1280;          // [32][40] shorts

  const unsigned short* Qg = Q + ((size_t)b * N_ + q0 + w * 32) * 256;
  const unsigned short* Kg = K + ((size_t)b * N_ + kvbase) * 256;
  const unsigned short* Vg = V + (size_t)b * 256 * N_ + kvbase;
  const float sc = 0.0625f * 1.44269504088896f;          // C^-0.5 * log2(e)

  // hoist Q fragments: 2 row-blocks x 8 k-steps
  s8v qf[2][8];
  #pragma unroll
  for (int rb = 0; rb < 2; ++rb)
    #pragma unroll
    for (int kt = 0; kt < 8; ++kt)
      qf[rb][kt] = *(const s8v*)(Qg + (size_t)(rb * 16 + l15) * 256 + kt * 32 + lg * 8);

  f32x4 o_acc[2][16];
  #pragma unroll
  for (int rb = 0; rb < 2; ++rb)
    #pragma unroll
    for (int ct = 0; ct < 16; ++ct) o_acc[rb][ct] = f32x4{0.f, 0.f, 0.f, 0.f};
  float m_r[2][4], l_r[2][4];
  #pragma unroll
  for (int rb = 0; rb < 2; ++rb)
    #pragma unroll
    for (int r = 0; r < 4; ++r) { m_r[rb][r] = -1e30f; l_r[rb][r] = 0.f; }

  // async stage: K tile [32][256] (source pre-swizzled), V tile [256][32]
  auto stage = [&](int it, int bufsel) {
    unsigned short* Kd = smem + bufsel * 8192;
    unsigned short* Vd = smem + 16384 + bufsel * 8192;
    const unsigned short* Ks = Kg + (size_t)it * 32 * 256;
    const unsigned short* Vs = Vg + it * 32;
    #pragma unroll
    for (int i = 0; i < 4; ++i) {
      int slot = i * 256 + t;
      int mm = slot >> 5, c = slot & 31;
      const unsigned short* src = Ks + (size_t)mm * 256 + ((c ^ (mm & 7)) << 3);
      unsigned short* dst = Kd + (i * 256 + w * 64) * 8;
      __builtin_amdgcn_global_load_lds(
          (const __attribute__((address_space(1))) u32*)src,
          (__attribute__((address_space(3))) u32*)dst, 16, 0, 0);
    }
    #pragma unroll
    for (int i = 0; i < 4; ++i) {
      int slot = i * 256 + t;
      int cc = slot >> 2, c = slot & 3;
      const unsigned short* src = Vs + (size_t)cc * N_ + c * 8;
      unsigned short* dst = Vd + (i * 256 + w * 64) * 8;
      __builtin_amdgcn_global_load_lds(
          (const __attribute__((address_space(1))) u32*)src,
          (__attribute__((address_space(3))) u32*)dst, 16, 0, 0);
    }
  };

  stage(0, 0);
  __syncthreads();

  for (int it = 0; it < 64; ++it) {
    int cur = it & 1;
    if (it + 1 < 64) stage(it + 1, cur ^ 1);   // prefetch into other buffer
    const unsigned short* Kd = smem + cur * 8192;
    const unsigned short* Vd = smem + 16384 + cur * 8192;

    // S = Q K^T : 2 row-blocks x 2 col-tiles, K-frags shared across row-blocks
    f32x4 sv[2][2];
    #pragma unroll
    for (int rb = 0; rb < 2; ++rb)
      #pragma unroll
      for (int jt = 0; jt < 2; ++jt) sv[rb][jt] = f32x4{0.f, 0.f, 0.f, 0.f};
    #pragma unroll
    for (int kt = 0; kt < 8; ++kt) {
      #pragma unroll
      for (int jt = 0; jt < 2; ++jt) {
        int row = jt * 16 + l15;
        s8v kb = *(const s8v*)((const char*)Kd + row * 512 +
                               ((kt * 64 + lg * 16) ^ ((row & 7) << 4)));
        sv[0][jt] = __builtin_amdgcn_mfma_f32_16x16x32_bf16(qf[0][kt], kb, sv[0][jt], 0, 0, 0);
        sv[1][jt] = __builtin_amdgcn_mfma_f32_16x16x32_bf16(qf[1][kt], kb, sv[1][jt], 0, 0, 0);
      }
    }

    // online softmax (log2 domain), defer-max rescale (T13, THR=8)
    float rm[2][4];
    #pragma unroll
    for (int rb = 0; rb < 2; ++rb)
      #pragma unroll
      for (int r = 0; r < 4; ++r) rm[rb][r] = fmaxf(sv[rb][0][r], sv[rb][1][r]);
    #pragma unroll
    for (int o = 1; o < 16; o <<= 1)
      #pragma unroll
      for (int rb = 0; rb < 2; ++rb)
        #pragma unroll
        for (int r = 0; r < 4; ++r) rm[rb][r] = fmaxf(rm[rb][r], __shfl_xor(rm[rb][r], o));
    bool ok = true;
    #pragma unroll
    for (int rb = 0; rb < 2; ++rb)
      #pragma unroll
      for (int r = 0; r < 4; ++r) {
        rm[rb][r] *= sc;
        ok = ok && (rm[rb][r] <= m_r[rb][r] + 8.f);
      }
    if (!__all(ok)) {
      float cr[2][4];
      #pragma unroll
      for (int rb = 0; rb < 2; ++rb)
        #pragma unroll
        for (int r = 0; r < 4; ++r) {
          float mn = fmaxf(m_r[rb][r], rm[rb][r]);
          cr[rb][r] = exp2f(m_r[rb][r] - mn);
          m_r[rb][r] = mn;
          l_r[rb][r] *= cr[rb][r];
        }
      #pragma unroll
      for (int rb = 0; rb < 2; ++rb)
        #pragma unroll
        for (int ct = 0; ct < 16; ++ct)
          #pragma unroll
          for (int r = 0; r < 4; ++r) o_acc[rb][ct][r] *= cr[rb][r];
    }
    float rs[2][4];
    #pragma unroll
    for (int rb = 0; rb < 2; ++rb)
      #pragma unroll
      for (int r = 0; r < 4; ++r) rs[rb][r] = 0.f;
    #pragma unroll
    for (int rb = 0; rb < 2; ++rb)
      #pragma unroll
      for (int jt = 0; jt < 2; ++jt)
        #pragma unroll
        for (int r = 0; r < 4; ++r) {
          float p = exp2f(__builtin_fmaf(sv[rb][jt][r], sc, -m_r[rb][r]));
          sv[rb][jt][r] = p;
          rs[rb][r] += p;
        }
    #pragma unroll
    for (int o = 1; o < 16; o <<= 1)
      #pragma unroll
      for (int rb = 0; rb < 2; ++rb)
        #pragma unroll
        for (int r = 0; r < 4; ++r) rs[rb][r] += __shfl_xor(rs[rb][r], o);
    #pragma unroll
    for (int rb = 0; rb < 2; ++rb)
      #pragma unroll
      for (int r = 0; r < 4; ++r) l_r[rb][r] += rs[rb][r];

    // P -> wave-private LDS [32][40] (conflict-free by stride), read back A-frags
    #pragma unroll
    for (int rb = 0; rb < 2; ++rb)
      #pragma unroll
      for (int jt = 0; jt < 2; ++jt)
        #pragma unroll
        for (int r = 0; r < 4; ++r)
          Pw[(rb * 16 + lg * 4 + r) * 40 + jt * 16 + l15] = f2bf(sv[rb][jt][r]);
    s8v pa[2];
    #pragma unroll
    for (int rb = 0; rb < 2; ++rb)
      pa[rb] = *(const s8v*)(Pw + (rb * 16 + l15) * 40 + lg * 8);

    // O += P V : V-frags shared across row-blocks
    #pragma unroll
    for (int ct = 0; ct < 16; ++ct) {
      s8v vb = *(const s8v*)(Vd + (ct * 16 + l15) * 32 + lg * 8);
      o_acc[0][ct] = __builtin_amdgcn_mfma_f32_16x16x32_bf16(pa[0], vb, o_acc[0][ct], 0, 0, 0);
      o_acc[1][ct] = __builtin_amdgcn_mfma_f32_16x16x32_bf16(pa[1], vb, o_acc[1][ct], 0, 0, 0);
    }
    __syncthreads();
  }

  // epilogue: normalized bf16 partial + LSE
  #pragma unroll
  for (int rb = 0; rb < 2; ++rb) {
    float inv[4];
    #pragma unroll
    for (int r = 0; r < 4; ++r) inv[r] = 1.f / l_r[rb][r];
    int rid0 = b * N_ + q0 + w * 32 + rb * 16;
    if (l15 == 0) {
      #pragma unroll
      for (int r = 0; r < 4; ++r)
        lse[sl * (B_ * N_) + rid0 + lg * 4 + r] = m_r[rb][r] + log2f(l_r[rb][r]);
    }
    unsigned short* Od = Op + ((size_t)sl * (B_ * N_) + rid0) * 256;
    #pragma unroll
    for (int ct = 0; ct < 16; ++ct)
      #pragma unroll
      for (int r = 0; r < 4; ++r)
        Od[(size_t)(lg * 4 + r) * 256 + ct * 16 + l15] = f2bf(o_acc[rb][ct][r] * inv[r]);
  }
}

// ---------------- merge the 4 KV-slice partials ------------------------------
__global__ __launch_bounds__(256) void attn_merge_kernel(
    const unsigned short* __restrict__ Op, const float* __restrict__ lse,
    unsigned short* __restrict__ Ob) {
  int gid = blockIdx.x * 256 + threadIdx.x;      // 524288 = 16384 rows x 32 chunks
  int row = gid >> 5;
  int co = (gid & 31) * 8;
  float L[4], lm = -1e30f;
  #pragma unroll
  for (int s = 0; s < 4; ++s) { L[s] = lse[s * (B_ * N_) + row]; lm = fmaxf(lm, L[s]); }
  float acc[8];
  #pragma unroll
  for (int e = 0; e < 8; ++e) acc[e] = 0.f;
  float wsum = 0.f;
  #pragma unroll
  for (int s = 0; s < 4; ++s) {
    float wg = exp2f(L[s] - lm);
    wsum += wg;
    s8v v = *(const s8v*)(Op + ((size_t)s * (B_ * N_) + row) * 256 + co);
    #pragma unroll
    for (int e = 0; e < 8; ++e) acc[e] += wg * bf2f((unsigned short)v[e]);
  }
  float inv = 1.f / wsum;
  s8v o;
  #pragma unroll
  for (int e = 0; e < 8; ++e) o[e] = (short)f2bf(acc[e] * inv);
  *(s8v*)(Ob + (size_t)row * 256 + co) = o;
}

// ---------------------------------------------------------------------------
extern "C" void kernel_launch(void* const* d_in, const int* in_sizes, int n_in,
                              void* d_out, int out_size, void* d_ws, size_t ws_size,
                              hipStream_t stream) {
  (void)in_sizes; (void)n_in; (void)out_size; (void)ws_size;
  const float* x  = (const float*)d_in[0];
  const float* gw = (const float*)d_in[1];
  const float* gb = (const float*)d_in[2];
  const float* wq = (const float*)d_in[3];
  const float* bq = (const float*)d_in[4];
  const float* wk = (const float*)d_in[5];
  const float* bk = (const float*)d_in[6];
  const float* wv = (const float*)d_in[7];
  const float* bv = (const float*)d_in[8];
  const float* wp = (const float*)d_in[9];
  const float* bp = (const float*)d_in[10];

  const size_t HS = (size_t)N_ * C_;              // per-batch elems
  char* ws = (char*)d_ws;
  unsigned short* wqb = (unsigned short*)ws;             // 512 KB
  float* meanp = (float*)(ws + 524288);
  float* rstdp = meanp + 64;
  unsigned short* h    = (unsigned short*)(ws + 525312); // 8 MB  [B][N][C]
  unsigned short* Qb   = h  + B_ * HS;                   // 8 MB  [B][N][C]
  unsigned short* Kb   = Qb + B_ * HS;                   // 8 MB  [B][N][C]
  unsigned short* Vb   = Kb + B_ * HS;                   // 8 MB  [B][C][N]
  unsigned short* Ob   = Vb + B_ * HS;                   // 8 MB  [B][N][C]
  unsigned short* Opart = Ob + B_ * HS;                  // 32 MB [4][B*N][C]
  float* lsep = (float*)(Opart + 4 * B_ * HS);           // 256 KB [4][B*N]
  // total ws use ~72.8 MB

  cvt_w_kernel<<<1024, 256, 0, stream>>>(wq, wk, wv, wp, wqb);
  gn_stats_kernel<<<B_ * NG_, 256, 0, stream>>>(x, meanp, rstdp);
  gn_apply_kernel<<<dim3(N_ / 64, B_), 256, 0, stream>>>(x, gw, gb, meanp, rstdp, h);

  unsigned short* wkb = wqb + 65536;
  unsigned short* wvb = wkb + 65536;
  unsigned short* wpb = wvb + 65536;
  gemm_nt_kernel<0><<<dim3(N_ / 64, C_ / 64, B_), 256, 0, stream>>>(
      h, (long)HS, wqb, 0, bq, nullptr, 0, Qb, (long)HS, C_);
  gemm_nt_kernel<0><<<dim3(N_ / 64, C_ / 64, B_), 256, 0, stream>>>(
      h, (long)HS, wkb, 0, bk, nullptr, 0, Kb, (long)HS, C_);
  gemm_nt_kernel<1><<<dim3(C_ / 64, N_ / 64, B_), 256, 0, stream>>>(
      wvb, 0, h, (long)HS, bv, nullptr, 0, Vb, (long)HS, N_);

  // flash attention pass 1: 4 KV slices, dbuf LDS = 75776 B
  const int attn_lds = 75776;
  hipFuncSetAttribute(reinterpret_cast<const void*>(attn_kernel),
                      hipFuncAttributeMaxDynamicSharedMemorySize, attn_lds);
  attn_kernel<<<dim3(N_ / 128, 4, B_), 256, attn_lds, stream>>>(Qb, Kb, Vb, Opart, lsep);

  // merge 4 slices -> Ob
  attn_merge_kernel<<<(B_ * N_ * 32) / 256, 256, 0, stream>>>(Opart, lsep, Ob);

  // out[o][n] = wp . O[n][:] + bp + x
  gemm_nt_kernel<2><<<dim3(C_ / 64, N_ / 64, B_), 256, 0, stream>>>(
      wpb, 0, Ob, (long)HS, bp, x, (long)HS, d_out, (long)HS, N_);
}

// Round 7
// 295.423 us; speedup vs baseline: 1.4985x; 1.4942x over previous
//
#include <hip/hip_runtime.h>

#define B_ 2
#define C_ 256
#define N_ 8192
#define NG_ 32

typedef unsigned int u32;
using f32x4  = __attribute__((ext_vector_type(4))) float;
using f32x16 = __attribute__((ext_vector_type(16))) float;
using s8v    = __attribute__((ext_vector_type(8))) short;   // 8 x bf16
using u32x2  = __attribute__((ext_vector_type(2))) u32;

__device__ __forceinline__ unsigned short f2bf(float f) {
  unsigned u = __builtin_bit_cast(unsigned, f);
  return (unsigned short)((u + 0x7fffu + ((u >> 16) & 1u)) >> 16);
}
__device__ __forceinline__ float bf2f(unsigned short h) {
  return __builtin_bit_cast(float, (u32)h << 16);
}

// ---------------- weight fp32 -> bf16 (4 x 256x256, contiguous out) ---------
__global__ void cvt_w_kernel(const float* __restrict__ wq, const float* __restrict__ wk,
                             const float* __restrict__ wv, const float* __restrict__ wp,
                             unsigned short* __restrict__ out) {
  int i = blockIdx.x * 256 + threadIdx.x;        // 262144 total
  int m = i >> 16;
  const float* src = m == 0 ? wq : m == 1 ? wk : m == 2 ? wv : wp;
  out[i] = f2bf(src[i & 65535]);
}

// ---------------- groupnorm pass 1: mean/rstd per (b, group) ----------------
__global__ void gn_stats_kernel(const float* __restrict__ x,
                                float* __restrict__ mean, float* __restrict__ rstd) {
  int bg = blockIdx.x;                                  // 64 groups total
  const f32x4* p = (const f32x4*)(x + (size_t)bg * (8 * N_));
  float s = 0.f, sq = 0.f;
  for (int i = threadIdx.x; i < 8 * N_ / 4; i += 256) {
    f32x4 v = p[i];
    s  += v.x + v.y + v.z + v.w;
    sq += v.x * v.x + v.y * v.y + v.z * v.z + v.w * v.w;
  }
  #pragma unroll
  for (int o = 32; o; o >>= 1) { s += __shfl_down(s, o); sq += __shfl_down(sq, o); }
  __shared__ float ls[4], lq[4];
  int w = threadIdx.x >> 6;
  if ((threadIdx.x & 63) == 0) { ls[w] = s; lq[w] = sq; }
  __syncthreads();
  if (threadIdx.x == 0) {
    s = ls[0] + ls[1] + ls[2] + ls[3];
    sq = lq[0] + lq[1] + lq[2] + lq[3];
    float m = s / (8.f * N_);
    float var = sq / (8.f * N_) - m * m;
    mean[bg] = m;
    rstd[bg] = rsqrtf(var + 1e-5f);
  }
}

// -------- groupnorm pass 2: normalize + transpose -> h[N][C] bf16 -----------
__global__ __launch_bounds__(256) void gn_apply_kernel(
    const float* __restrict__ x, const float* __restrict__ gw, const float* __restrict__ gb,
    const float* __restrict__ mean, const float* __restrict__ rstd,
    unsigned short* __restrict__ h) {
  __shared__ unsigned short lds[256][72];
  int b = blockIdx.y, n0 = blockIdx.x * 64;
  const float* xb = x + (size_t)b * C_ * N_;
  int col = threadIdx.x & 63;
  int c0  = threadIdx.x >> 6;
  for (int r = 0; r < 64; ++r) {
    int c = r * 4 + c0;
    float v = xb[(size_t)c * N_ + n0 + col];
    int g = b * NG_ + (c >> 3);
    lds[c][col] = f2bf((v - mean[g]) * rstd[g] * gw[c] + gb[c]);
  }
  __syncthreads();
  int nl = threadIdx.x >> 2;                      // 0..63
  int cb = threadIdx.x & 3;                       // 0..3 (64-channel chunk)
  unsigned short* dst = h + ((size_t)b * N_ + n0 + nl) * C_ + cb * 64;
  #pragma unroll
  for (int g2 = 0; g2 < 8; ++g2) {
    s8v v;
    #pragma unroll
    for (int e = 0; e < 8; ++e) v[e] = (short)lds[cb * 64 + g2 * 8 + e][nl];
    *(s8v*)(dst + g2 * 8) = v;
  }
}

// -------- generic C[i][j] = sum_k A[i][k]*B[j][k] (bf16 in, K=256) ----------
template <int MODE>
__global__ __launch_bounds__(256) void gemm_nt_kernel(
    const unsigned short* __restrict__ A, long sA,
    const unsigned short* __restrict__ Bm, long sB,
    const float* __restrict__ bias,
    const float* __restrict__ resid, long sR,
    void* __restrict__ outv, long sO, int ldo) {
  int b = blockIdx.z;
  const unsigned short* Ab = A + (size_t)b * sA;
  const unsigned short* Bb = Bm + (size_t)b * sB;
  int i0 = blockIdx.x * 64, j0 = blockIdx.y * 64;
  int lane = threadIdx.x & 63, w = threadIdx.x >> 6;
  int l15 = lane & 15, lg = lane >> 4;
  const unsigned short* Ap = Ab + (size_t)(i0 + w * 16 + l15) * 256 + lg * 8;
  const unsigned short* Bp = Bb + (size_t)(j0 + l15) * 256 + lg * 8;
  f32x4 acc[4];
  #pragma unroll
  for (int jt = 0; jt < 4; ++jt) acc[jt] = f32x4{0.f, 0.f, 0.f, 0.f};
  #pragma unroll
  for (int kt = 0; kt < 8; ++kt) {
    s8v a = *(const s8v*)(Ap + kt * 32);
    #pragma unroll
    for (int jt = 0; jt < 4; ++jt) {
      s8v bb = *(const s8v*)(Bp + (size_t)jt * 16 * 256 + kt * 32);
      acc[jt] = __builtin_amdgcn_mfma_f32_16x16x32_bf16(a, bb, acc[jt], 0, 0, 0);
    }
  }
  int rowb = i0 + w * 16 + lg * 4;
  if (MODE == 0) {
    unsigned short* o = (unsigned short*)outv + (size_t)b * sO;
    #pragma unroll
    for (int jt = 0; jt < 4; ++jt) {
      int j = j0 + jt * 16 + l15;
      float bj = bias[j];
      #pragma unroll
      for (int r = 0; r < 4; ++r)
        o[(size_t)(rowb + r) * ldo + j] = f2bf(acc[jt][r] + bj);
    }
  } else if (MODE == 1) {
    unsigned short* o = (unsigned short*)outv + (size_t)b * sO;
    #pragma unroll
    for (int jt = 0; jt < 4; ++jt) {
      int j = j0 + jt * 16 + l15;
      #pragma unroll
      for (int r = 0; r < 4; ++r)
        o[(size_t)(rowb + r) * ldo + j] = f2bf(acc[jt][r] + bias[rowb + r]);
    }
  } else {
    float* o = (float*)outv + (size_t)b * sO;
    const float* xr = resid + (size_t)b * sR;
    #pragma unroll
    for (int jt = 0; jt < 4; ++jt) {
      int j = j0 + jt * 16 + l15;
      #pragma unroll
      for (int r = 0; r < 4; ++r) {
        size_t idx = (size_t)(rowb + r) * ldo + j;
        o[idx] = acc[jt][r] + bias[rowb + r] + xr[idx];
      }
    }
  }
}

// ---------------- flash attention pass 1 (swapped-QK^T, 32x32 MFMA) ---------
// 256 thr = 4 waves, 32 q-rows/wave (QBLK=128). KVBLK=32, 4 KV slices.
// S^T = mfma(K, Q): q = lane&31 -> softmax fully lane-local (m,l scalar/lane).
// P -> PV B-frags in-register (8 shfl_xor(32) + selects). O^T = mfma(V^T, P).
// K LDS [32 rows][32 slots], slot^=row full-XOR swizzle (pre-swizzled global
// source, linear global_load_lds dest) -> conflict-free. V LDS [kv/8][d][8]
// -> conflict-free by construction. LDS = 2x16K (K) + 2x16K (V) = 65536 B.
__global__ __launch_bounds__(256, 2) void attn_kernel(
    const unsigned short* __restrict__ Q, const unsigned short* __restrict__ K,
    const unsigned short* __restrict__ V, unsigned short* __restrict__ Op,
    float* __restrict__ lse) {
  extern __shared__ unsigned short smem[];
  // dispatch remap: consecutive blockIdx -> XCD round-robin; make each XCD's
  // resident set share one (sl,b) so its 2MB K/V slice fits the 4MB L2.
  int f = blockIdx.x;
  int grp = f & 7, qb = f >> 3;
  int sl = grp & 3, b = grp >> 2;
  int q0 = qb * 128;
  int kvbase = sl * 2048;
  int t = threadIdx.x, lane = t & 63, w = t >> 6;
  int l31 = lane & 31, hi = lane >> 5;

  const unsigned short* Qg = Q + ((size_t)b * N_ + q0 + w * 32 + l31) * 256;
  const unsigned short* Kg = K + ((size_t)b * N_ + kvbase) * 256;
  const unsigned short* Vg = V + (size_t)b * 256 * N_ + kvbase;
  const float sc = 0.0625f * 1.44269504088896f;          // C^-0.5 * log2(e)

  // Q as B-operand frags: col(q)=lane&31, k = hi*8+e ; 16 k-slots of 16
  s8v qf[16];
  #pragma unroll
  for (int tt = 0; tt < 16; ++tt)
    qf[tt] = *(const s8v*)(Qg + tt * 16 + hi * 8);

  f32x16 o_acc[8];                                       // O^T: d-chunk x 16
  #pragma unroll
  for (int dc = 0; dc < 8; ++dc)
    #pragma unroll
    for (int r = 0; r < 16; ++r) o_acc[dc][r] = 0.f;
  float m_r = -1e30f, l_r = 0.f;                          // per-lane (q=l31)

  auto stage = [&](int it, int bufsel) {
    char* Kd = (char*)smem + bufsel * 16384;
    char* Vd = (char*)smem + 32768 + bufsel * 16384;
    const unsigned short* Ks = Kg + (size_t)it * 32 * 256;
    const unsigned short* Vs = Vg + it * 32;
    #pragma unroll
    for (int i = 0; i < 4; ++i) {                        // K: row mm, slot j
      int u = i * 256 + t;
      int mm = u >> 5, j = u & 31;
      const unsigned short* src = Ks + mm * 256 + ((j ^ mm) * 8);  // pre-swizzle
      char* dst = Kd + (i * 256 + w * 64) * 16;          // linear dest
      __builtin_amdgcn_global_load_lds(
          (const __attribute__((address_space(1))) u32*)src,
          (__attribute__((address_space(3))) u32*)dst, 16, 0, 0);
    }
    #pragma unroll
    for (int i = 0; i < 4; ++i) {                        // V: [ko=i][d=t][8]
      const unsigned short* src = Vs + (size_t)t * N_ + i * 8;
      char* dst = Vd + (i * 256 + w * 64) * 16;
      __builtin_amdgcn_global_load_lds(
          (const __attribute__((address_space(1))) u32*)src,
          (__attribute__((address_space(3))) u32*)dst, 16, 0, 0);
    }
  };

  stage(0, 0);
  __syncthreads();

  for (int it = 0; it < 64; ++it) {
    int cur = it & 1;
    if (it + 1 < 64) stage(it + 1, cur ^ 1);             // prefetch other buf
    const char* Kd = (const char*)smem + cur * 16384;
    const char* Vd = (const char*)smem + 32768 + cur * 16384;

    // S^T[kv][q] = sum_c K[kv][c] Q[q][c]
    f32x16 sa;
    #pragma unroll
    for (int r = 0; r < 16; ++r) sa[r] = 0.f;
    __builtin_amdgcn_s_setprio(1);
    #pragma unroll
    for (int tt = 0; tt < 16; ++tt) {
      int slot = 2 * tt + hi;
      s8v ka = *(const s8v*)(Kd + l31 * 512 + ((slot ^ l31) * 16));
      sa = __builtin_amdgcn_mfma_f32_32x32x16_bf16(ka, qf[tt], sa, 0, 0, 0);
    }
    __builtin_amdgcn_s_setprio(0);

    // lane-local softmax (q = l31); kv split across lane halves
    float rmax = sa[0];
    #pragma unroll
    for (int r = 1; r < 16; ++r) rmax = fmaxf(rmax, sa[r]);
    rmax = fmaxf(rmax, __shfl_xor(rmax, 32));
    rmax *= sc;
    if (!__all(rmax <= m_r + 8.f)) {                     // defer-max (T13)
      float mn = fmaxf(m_r, rmax);
      float corr = exp2f(m_r - mn);
      m_r = mn;
      l_r *= corr;
      #pragma unroll
      for (int dc = 0; dc < 8; ++dc)
        #pragma unroll
        for (int r = 0; r < 16; ++r) o_acc[dc][r] *= corr;
    }
    float p[16], rs = 0.f;
    #pragma unroll
    for (int r = 0; r < 16; ++r) {
      p[r] = exp2f(__builtin_fmaf(sa[r], sc, -m_r));
      rs += p[r];
    }
    l_r += rs + __shfl_xor(rs, 32);

    // P -> bf16 words; cross-half exchange -> PV B-frags (k=kv)
    u32 wv[8], sw[8];
    #pragma unroll
    for (int j = 0; j < 8; ++j)
      wv[j] = (u32)f2bf(p[2 * j]) | ((u32)f2bf(p[2 * j + 1]) << 16);
    #pragma unroll
    for (int j = 0; j < 8; ++j) sw[j] = __shfl_xor(wv[j], 32);
    union { u32 u[4]; s8v v; } pf0, pf1;
    pf0.u[0] = hi ? sw[2] : wv[0];
    pf0.u[1] = hi ? sw[3] : wv[1];
    pf0.u[2] = hi ? wv[2] : sw[0];
    pf0.u[3] = hi ? wv[3] : sw[1];
    pf1.u[0] = hi ? sw[6] : wv[4];
    pf1.u[1] = hi ? sw[7] : wv[5];
    pf1.u[2] = hi ? wv[6] : sw[4];
    pf1.u[3] = hi ? wv[7] : sw[5];

    // O^T[d][q] += sum_kv V^T[d][kv] P[q][kv]
    __builtin_amdgcn_s_setprio(1);
    #pragma unroll
    for (int dc = 0; dc < 8; ++dc) {
      s8v va0 = *(const s8v*)(Vd + ((0 * 2 + hi) * 256 + dc * 32 + l31) * 16);
      o_acc[dc] = __builtin_amdgcn_mfma_f32_32x32x16_bf16(va0, pf0.v, o_acc[dc], 0, 0, 0);
      s8v va1 = *(const s8v*)(Vd + ((1 * 2 + hi) * 256 + dc * 32 + l31) * 16);
      o_acc[dc] = __builtin_amdgcn_mfma_f32_32x32x16_bf16(va1, pf1.v, o_acc[dc], 0, 0, 0);
    }
    __builtin_amdgcn_s_setprio(0);
    __syncthreads();
  }

  // epilogue: normalized bf16 partial + LSE (all per-lane scalars)
  float inv = 1.f / l_r;
  size_t rid = (size_t)b * N_ + q0 + w * 32 + l31;
  if (!hi) lse[(size_t)sl * (B_ * N_) + rid] = m_r + log2f(l_r);
  unsigned short* Od = Op + ((size_t)sl * (B_ * N_) + rid) * 256;
  #pragma unroll
  for (int dc = 0; dc < 8; ++dc) {
    #pragma unroll
    for (int rg = 0; rg < 4; ++rg) {
      int d0 = dc * 32 + 8 * rg + 4 * hi;                // 4 consecutive d
      u32 w0 = (u32)f2bf(o_acc[dc][rg * 4 + 0] * inv) |
               ((u32)f2bf(o_acc[dc][rg * 4 + 1] * inv) << 16);
      u32 w1 = (u32)f2bf(o_acc[dc][rg * 4 + 2] * inv) |
               ((u32)f2bf(o_acc[dc][rg * 4 + 3] * inv) << 16);
      u32x2 pk{w0, w1};
      *(u32x2*)(Od + d0) = pk;
    }
  }
}

// ---------------- merge the 4 KV-slice partials ------------------------------
__global__ __launch_bounds__(256) void attn_merge_kernel(
    const unsigned short* __restrict__ Op, const float* __restrict__ lse,
    unsigned short* __restrict__ Ob) {
  int gid = blockIdx.x * 256 + threadIdx.x;      // 524288 = 16384 rows x 32 chunks
  int row = gid >> 5;
  int co = (gid & 31) * 8;
  float L[4], lm = -1e30f;
  #pragma unroll
  for (int s = 0; s < 4; ++s) { L[s] = lse[s * (B_ * N_) + row]; lm = fmaxf(lm, L[s]); }
  float acc[8];
  #pragma unroll
  for (int e = 0; e < 8; ++e) acc[e] = 0.f;
  float wsum = 0.f;
  #pragma unroll
  for (int s = 0; s < 4; ++s) {
    float wg = exp2f(L[s] - lm);
    wsum += wg;
    s8v v = *(const s8v*)(Op + ((size_t)s * (B_ * N_) + row) * 256 + co);
    #pragma unroll
    for (int e = 0; e < 8; ++e) acc[e] += wg * bf2f((unsigned short)v[e]);
  }
  float inv = 1.f / wsum;
  s8v o;
  #pragma unroll
  for (int e = 0; e < 8; ++e) o[e] = (short)f2bf(acc[e] * inv);
  *(s8v*)(Ob + (size_t)row * 256 + co) = o;
}

// ---------------------------------------------------------------------------
extern "C" void kernel_launch(void* const* d_in, const int* in_sizes, int n_in,
                              void* d_out, int out_size, void* d_ws, size_t ws_size,
                              hipStream_t stream) {
  (void)in_sizes; (void)n_in; (void)out_size; (void)ws_size;
  const float* x  = (const float*)d_in[0];
  const float* gw = (const float*)d_in[1];
  const float* gb = (const float*)d_in[2];
  const float* wq = (const float*)d_in[3];
  const float* bq = (const float*)d_in[4];
  const float* wk = (const float*)d_in[5];
  const float* bk = (const float*)d_in[6];
  const float* wv = (const float*)d_in[7];
  const float* bv = (const float*)d_in[8];
  const float* wp = (const float*)d_in[9];
  const float* bp = (const float*)d_in[10];

  const size_t HS = (size_t)N_ * C_;              // per-batch elems
  char* ws = (char*)d_ws;
  unsigned short* wqb = (unsigned short*)ws;             // 512 KB
  float* meanp = (float*)(ws + 524288);
  float* rstdp = meanp + 64;
  unsigned short* h    = (unsigned short*)(ws + 525312); // 8 MB  [B][N][C]
  unsigned short* Qb   = h  + B_ * HS;                   // 8 MB  [B][N][C]
  unsigned short* Kb   = Qb + B_ * HS;                   // 8 MB  [B][N][C]
  unsigned short* Vb   = Kb + B_ * HS;                   // 8 MB  [B][C][N]
  unsigned short* Ob   = Vb + B_ * HS;                   // 8 MB  [B][N][C]
  unsigned short* Opart = Ob + B_ * HS;                  // 32 MB [4][B*N][C]
  float* lsep = (float*)(Opart + 4 * B_ * HS);           // 256 KB [4][B*N]

  cvt_w_kernel<<<1024, 256, 0, stream>>>(wq, wk, wv, wp, wqb);
  gn_stats_kernel<<<B_ * NG_, 256, 0, stream>>>(x, meanp, rstdp);
  gn_apply_kernel<<<dim3(N_ / 64, B_), 256, 0, stream>>>(x, gw, gb, meanp, rstdp, h);

  unsigned short* wkb = wqb + 65536;
  unsigned short* wvb = wkb + 65536;
  unsigned short* wpb = wvb + 65536;
  gemm_nt_kernel<0><<<dim3(N_ / 64, C_ / 64, B_), 256, 0, stream>>>(
      h, (long)HS, wqb, 0, bq, nullptr, 0, Qb, (long)HS, C_);
  gemm_nt_kernel<0><<<dim3(N_ / 64, C_ / 64, B_), 256, 0, stream>>>(
      h, (long)HS, wkb, 0, bk, nullptr, 0, Kb, (long)HS, C_);
  gemm_nt_kernel<1><<<dim3(C_ / 64, N_ / 64, B_), 256, 0, stream>>>(
      wvb, 0, h, (long)HS, bv, nullptr, 0, Vb, (long)HS, N_);

  // flash attention pass 1: swapped-QK^T 32x32, 4 KV slices, 65536 B LDS
  const int attn_lds = 65536;
  hipFuncSetAttribute(reinterpret_cast<const void*>(attn_kernel),
                      hipFuncAttributeMaxDynamicSharedMemorySize, attn_lds);
  attn_kernel<<<dim3(512), 256, attn_lds, stream>>>(Qb, Kb, Vb, Opart, lsep);

  // merge 4 slices -> Ob
  attn_merge_kernel<<<(B_ * N_ * 32) / 256, 256, 0, stream>>>(Opart, lsep, Ob);

  // out[o][n] = wp . O[n][:] + bp + x
  gemm_nt_kernel<2><<<dim3(C_ / 64, N_ / 64, B_), 256, 0, stream>>>(
      wpb, 0, Ob, (long)HS, bp, x, (long)HS, d_out, (long)HS, N_);
}